// Round 1
// baseline (443.432 us; speedup 1.0000x reference)
//
#include <hip/hip_runtime.h>

typedef short short8  __attribute__((ext_vector_type(8)));
typedef short shortx4 __attribute__((ext_vector_type(4)));
typedef float floatx4 __attribute__((ext_vector_type(4)));
typedef unsigned short u16;

static __device__ __forceinline__ float bits2f(u16 s) {
    return __builtin_bit_cast(float, (unsigned)s << 16);
}
static __device__ __forceinline__ u16 f2bits(float f) {
    return __builtin_bit_cast(u16, (__bf16)f);   // RNE
}

#define SS 16

// ---- weight prepack ------------------------------------------------------
// wt0f [9][192][32] bf16 : ko<128 from W0, ko>=128 from R0 (fused layer-0)
// wt1  [9][128][64] bf16
// b192 : b0(128) ++ zeros(64)
__global__ void prep_kernel(const float* W0, const float* R0, const float* W1,
                            const float* b0, u16* wt0f, u16* wt1, float* b192) {
    const int i = blockIdx.x * 256 + threadIdx.x;
    if (i < 55296) {
        const int t = i / 6144, r = i % 6144, ko = r >> 5, ci = r & 31;
        wt0f[i] = f2bits(ko < 128 ? W0[(ko * 32 + ci) * 9 + t]
                                  : R0[((ko - 128) * 32 + ci) * 9 + t]);
    } else if (i < 55296 + 73728) {
        const int j = i - 55296;
        const int t = j / 8192, r = j % 8192, ko = r >> 6, ci = r & 63;
        wt1[j] = f2bits(W1[(ko * 64 + ci) * 9 + t]);
    } else if (i < 55296 + 73728 + 192) {
        const int j = i - 129024;
        b192[j] = (j < 128) ? b0[j] : 0.0f;
    }
}

// ---- x (64,32,64,64) f32 NCHW -> xT (64,64,64,32) bf16 NHWC ---------------
__global__ void transpose_kernel(const float* __restrict__ x, u16* __restrict__ xT) {
    const int img = blockIdx.x >> 6, h = blockIdx.x & 63;
    const int gq = threadIdx.x & 3, w = threadIdx.x >> 2;
    short8 o;
#pragma unroll
    for (int k = 0; k < 8; ++k)
        o[k] = (short)f2bits(x[((size_t)img * 32 + gq * 8 + k) * 4096 + h * 64 + w]);
    ((short8*)xT)[((size_t)(img * 64 + h) * 64 + w) * 4 + gq] = o;
}

// ---- MFMA implicit-GEMM 3x3 conv, pad 1, NHWC -----------------------------
// X (64,64,64,CI) bf16 NHWC; wt [9][KO][CI] bf16; bias (KO) f32;
// Y (64,64,64,KO) bf16 NHWC. Block 256 = 4 waves; one image x 4-row strip.
// Staging: global_load_lds w=16, linear LDS dest + pre-swizzled global src
// (source permutation == read swizzle (q+col)&(CG-1), both-sides rule).
// Weights: JIT 1-deep double buffer (af 72->~24 VGPR, no spill risk).
// NT stores only on KO=128 (A/B vs plain stores on the fused kernel).
template<int CI, int KO>
__global__ __launch_bounds__(256, 2)
void conv3x3_mfma_kernel(const u16* __restrict__ X, const u16* __restrict__ wt,
                         const float* __restrict__ bias, u16* __restrict__ Y) {
    constexpr int CG  = CI / 8;            // 16B ci-granules per pixel
    constexpr int CGS = (CG == 4) ? 2 : 3; // log2(CG)
    constexpr int KPW = KO / 64;           // 16-ko groups per wave
    constexpr int NG  = KO / 8;            // 16B ko-granules per pixel (out)
    constexpr int PXS = NG + 1;            // padded pixel stride (granules)
    constexpr int SG  = 6 * 66 * CG;       // staging granules
    constexpr int EPG = 128 * PXS;         // epilogue granules (2 rows x 64 px)
    constexpr int LSZ = (SG > EPG) ? SG : EPG;
    constexpr bool USE_NT = (KO == 128);
    __shared__ short8 lds[LSZ];

    const int l   = threadIdx.x & 63;
    const int wv  = threadIdx.x >> 6;
    const int c16 = l & 15;
    const int q16 = l >> 4;
    const int h0  = blockIdx.x * 4;
    const int n   = blockIdx.y;

    // zero staging LDS (borders + out-of-range rows stay zero)
    {
        const short8 z = {0, 0, 0, 0, 0, 0, 0, 0};
        for (int i = threadIdx.x; i < SG; i += 256) lds[i] = z;
    }
    __syncthreads();

    // stage rows h0-1..h0+4: one global_load_lds (64 lanes x 16B) per task.
    // LDS dest is linear from wave-uniform base; the per-pixel granule
    // swizzle is folded into the per-lane GLOBAL source address.
    const short8* Xg = (const short8*)X;
    {
        const int a = l >> CGS;          // pixel within chunk
        const int s = l & (CG - 1);      // dest slot within pixel
        for (int task = wv; task < 6 * CG; task += 4) {
            const int r     = task >> CGS;       // CG chunks per row
            const int chunk = task & (CG - 1);
            const int h     = h0 + r - 1;
            if (h >= 0 && h < 64) {              // wave-uniform
                const int col0 = 1 + chunk * (64 / CG);
                const int col  = col0 + a;
                const int q    = (s - col) & (CG - 1);   // src granule
                const short8* src =
                    Xg + ((size_t)(n * 64 + h) * 64 + (col - 1)) * CG + q;
                __builtin_amdgcn_global_load_lds(
                    (const __attribute__((address_space(1))) void*)src,
                    (__attribute__((address_space(3))) void*)(lds + (r * 66 + col0) * CG),
                    16, 0, 0);
            }
        }
    }

    // overlap with in-flight DMA: acc init + first weight prefetch
    const int kogb = wv * KPW;
    floatx4 acc[KPW][16];
#pragma unroll
    for (int kpw = 0; kpw < KPW; ++kpw) {
        const floatx4 init = *(const floatx4*)(bias + (kogb + kpw) * 16 + q16 * 4);
#pragma unroll
        for (int p = 0; p < 16; ++p) acc[kpw][p] = init;
    }
    const short8* wtv = (const short8*)wt;
    short8 afn[KPW];
#pragma unroll
    for (int kpw = 0; kpw < KPW; ++kpw)     // (t=0, ch=0)
        afn[kpw] = wtv[(size_t)((kogb + kpw) * 16 + c16) * CG + q16];
    __syncthreads();

#pragma unroll
    for (int ch = 0; ch < CI / 32; ++ch) {
#pragma unroll
        for (int t = 0; t < 9; ++t) {
            short8 afc[KPW];
#pragma unroll
            for (int kpw = 0; kpw < KPW; ++kpw) afc[kpw] = afn[kpw];
            // prefetch next tap (or next ch's tap 0) — compile-time indices
            if (!(t == 8 && ch == CI / 32 - 1)) {
                const int tn  = (t == 8) ? 0 : t + 1;
                const int chn = (t == 8) ? ch + 1 : ch;
#pragma unroll
                for (int kpw = 0; kpw < KPW; ++kpw)
                    afn[kpw] = wtv[(size_t)(tn * KO + (kogb + kpw) * 16 + c16) * CG
                                   + chn * 4 + q16];
            }
            const int dy = t / 3, dx = t - dy * 3;
#pragma unroll
            for (int p = 0; p < 16; ++p) {
                const int row = (p >> 2) + dy;
                const int col = (p & 3) * 16 + dx + c16;
                const int q   = ch * 4 + q16;
                const short8 bf = lds[(row * 66 + col) * CG + ((q + col) & (CG - 1))];
#pragma unroll
                for (int kpw = 0; kpw < KPW; ++kpw)
                    acc[kpw][p] = __builtin_amdgcn_mfma_f32_16x16x32_bf16(
                        afc[kpw], bf, acc[kpw][p], 0, 0, 0);
            }
        }
    }

    // epilogue: 2 rows at a time through LDS, then fully-coalesced stores
    shortx4* lq = (shortx4*)lds;
#pragma unroll
    for (int rp = 0; rp < 2; ++rp) {
        __syncthreads();   // staging reads (rp=0) / previous readback (rp=1) done
#pragma unroll
        for (int kpw = 0; kpw < KPW; ++kpw) {
            const int qoff = (kogb + kpw) * 4 + q16;
#pragma unroll
            for (int pp = 0; pp < 8; ++pp) {
                const int p   = rp * 8 + pp;
                const int pxl = ((p >> 2) & 1) * 64 + (p & 3) * 16 + c16;
                shortx4 ov;
#pragma unroll
                for (int r = 0; r < 4; ++r) ov[r] = (short)f2bits(acc[kpw][p][r]);
                lq[pxl * (2 * PXS) + qoff] = ov;
            }
        }
        __syncthreads();
#pragma unroll
        for (int i = 0; i < NG / 2; ++i) {
            const int L  = i * 256 + (int)threadIdx.x;
            const int px = L / NG, g = L % NG;
            const int h  = h0 + 2 * rp + (px >> 6);
            const int w  = px & 63;
            const short8 v = lds[px * PXS + g];
            short8* dst = (short8*)Y + ((size_t)(n * 64 + h) * 64 + w) * NG + g;
            if (USE_NT) __builtin_nontemporal_store(v, dst);
            else        *dst = v;
        }
    }
}

// ---- minGRU scan + residual, full batch, NHWC -----------------------------
// FINAL=0: Yg is fused (64,4096,192): gate [0,64), hidden [64,128), res [128,192).
//          out = x1 bf16 NHWC (64ch). R unused.
// FINAL=1: Yg is (64,4096,128): gate/hidden; R (64,4096,64) identity residual.
//          out = f32 NCHW via LDS transpose.
// hlast (B,64,HW) f32 via LDS transpose. Block: 16 hw x 16 cg.
template<bool FINAL>
__global__ void gru_kernel(const u16* __restrict__ Yg, const u16* __restrict__ R,
                           void* __restrict__ outp, float* __restrict__ hlast) {
    constexpr int YSTR = FINAL ? 32 : 48;   // shortx4 units per pixel
    __shared__ float lds_t[16 * 68];
    const int cg  = threadIdx.x & 15;
    const int hwl = threadIdx.x >> 4;
    const int b   = blockIdx.x >> 8;
    const int hwh = blockIdx.x & 255;
    const int hw  = hwh * 16 + hwl;
    const shortx4* Yv = (const shortx4*)Yg;
    const shortx4* Rv = (const shortx4*)R;
    float h[4] = {0.5f, 0.5f, 0.5f, 0.5f};
#pragma unroll
    for (int s = 0; s < SS; ++s) {
        const size_t px = (size_t)(b * 16 + s) * 4096 + hw;
        const shortx4 g4 = Yv[px * YSTR + cg];
        const shortx4 d4 = Yv[px * YSTR + 16 + cg];
        const shortx4 r4 = FINAL ? Rv[px * 16 + cg] : Yv[px * YSTR + 32 + cg];
        float o[4];
#pragma unroll
        for (int j = 0; j < 4; ++j) {
            const float g   = bits2f((u16)g4[j]);
            const float hid = bits2f((u16)d4[j]);
            const float z   = 1.0f / (1.0f + __expf(-g));
            const float gg  = (hid >= 0.0f) ? (hid + 0.5f) : (1.0f / (1.0f + __expf(-hid)));
            h[j] = h[j] + z * (gg - h[j]);             // (1-z)*h + z*gg
            o[j] = h[j] + bits2f((u16)r4[j]);
        }
        if (!FINAL) {
            shortx4 ov;
#pragma unroll
            for (int j = 0; j < 4; ++j) ov[j] = (short)f2bits(o[j]);
            ((shortx4*)outp)[px * 16 + cg] = ov;
        } else {
            floatx4 o4;
#pragma unroll
            for (int j = 0; j < 4; ++j) o4[j] = o[j];
            *(floatx4*)(&lds_t[hwl * 68 + cg * 4]) = o4;
            __syncthreads();
            const int c2 = threadIdx.x >> 2, h4 = threadIdx.x & 3;
            floatx4 v;
#pragma unroll
            for (int k = 0; k < 4; ++k) v[k] = lds_t[(h4 * 4 + k) * 68 + c2];
            *(floatx4*)((float*)outp +
                        ((size_t)(b * 16 + s) * 64 + c2) * 4096 + hwh * 16 + h4 * 4) = v;
            __syncthreads();
        }
    }
    // hlast: per-thread NHWC regs -> NCHW f32 via LDS transpose (64B segments)
    {
        floatx4 h4v;
#pragma unroll
        for (int j = 0; j < 4; ++j) h4v[j] = h[j];
        if (!FINAL) __syncthreads();   // FINAL path already synced at loop end
        *(floatx4*)(&lds_t[hwl * 68 + cg * 4]) = h4v;
        __syncthreads();
        const int c2 = threadIdx.x >> 2, h4 = threadIdx.x & 3;
        floatx4 v;
#pragma unroll
        for (int k = 0; k < 4; ++k) v[k] = lds_t[(h4 * 4 + k) * 68 + c2];
        *(floatx4*)(hlast + ((size_t)b * 64 + c2) * 4096 + hwh * 16 + h4 * 4) = v;
    }
}

extern "C" void kernel_launch(void* const* d_in, const int* in_sizes, int n_in,
                              void* d_out, int out_size, void* d_ws, size_t ws_size,
                              hipStream_t stream) {
    const float* x  = (const float*)d_in[0];   // (4,16,32,64,64)
    const float* W0 = (const float*)d_in[1];   // (128,32,3,3)
    const float* b0 = (const float*)d_in[2];   // (128,)
    const float* R0 = (const float*)d_in[3];   // (64,32,3,3)
    const float* W1 = (const float*)d_in[4];   // (128,64,3,3)
    const float* b1 = (const float*)d_in[5];   // (128,)

    float* out = (float*)d_out;                 // (4,16,64,64,64) NCHW f32
    float* h0o = out + (size_t)16777216;
    float* h1o = h0o + (size_t)1048576;

    char* ws = (char*)d_ws;
    u16*   wt0f = (u16*)ws;                             // 110,592 B
    u16*   wt1  = (u16*)(ws + 110592);                  // 147,456 B
    float* b192 = (float*)(ws + 258048);                // 768 B
    u16*   xT   = (u16*)(ws + (size_t)(1  << 20));      // 16 MiB (NHWC bf16 input)
    u16*   x1   = xT;                                   // 32 MiB; overwrites xT after conv
    u16*   y0   = (u16*)(ws + (size_t)(33 << 20));      // 96 MiB (fused 192ch) -> ends 129 MiB

    prep_kernel<<<505, 256, 0, stream>>>(W0, R0, W1, b0, wt0f, wt1, b192);
    transpose_kernel<<<4096, 256, 0, stream>>>(x, xT);

    // Layer 0 (full batch): fused gate/hidden/residual conv (192 ch) + scan -> x1
    conv3x3_mfma_kernel<32, 192><<<dim3(16, 64), 256, 0, stream>>>(xT, wt0f, b192, y0);
    gru_kernel<false><<<1024, 256, 0, stream>>>(y0, nullptr, x1, h0o);

    // Layer 1: conv from x1 -> y0 (reuse front 64 MiB), scan with identity residual
    conv3x3_mfma_kernel<64, 128><<<dim3(16, 64), 256, 0, stream>>>(x1, wt1, b1, y0);
    gru_kernel<true ><<<1024, 256, 0, stream>>>(y0, x1, out, h1o);
}

// Round 2
// 333.176 us; speedup vs baseline: 1.3309x; 1.3309x over previous
//
#include <hip/hip_runtime.h>

typedef short short8  __attribute__((ext_vector_type(8)));
typedef short shortx4 __attribute__((ext_vector_type(4)));
typedef float floatx4 __attribute__((ext_vector_type(4)));
typedef unsigned short u16;

static __device__ __forceinline__ float bits2f(u16 s) {
    return __builtin_bit_cast(float, (unsigned)s << 16);
}
static __device__ __forceinline__ u16 f2bits(float f) {
    return __builtin_bit_cast(u16, (__bf16)f);   // RNE
}

#define SS 16

// ---- weight prepack: wt[tap][ko][ci] bf16 + 64-entry zero bias ------------
__global__ void prep_kernel(const float* W0, const float* R0, const float* W1,
                            u16* wt0, u16* wtR, u16* wt1, float* zb) {
    const int i = blockIdx.x * 256 + threadIdx.x;
    if (i < 36864) {
        const int t = i / 4096, r = i % 4096, ko = r >> 5, ci = r & 31;
        wt0[i] = f2bits(W0[(ko * 32 + ci) * 9 + t]);
    } else if (i < 36864 + 18432) {
        const int j = i - 36864;
        const int t = j / 2048, r = j % 2048, ko = r >> 5, ci = r & 31;
        wtR[j] = f2bits(R0[(ko * 32 + ci) * 9 + t]);
    } else if (i < 36864 + 18432 + 73728) {
        const int j = i - 36864 - 18432;
        const int t = j / 8192, r = j % 8192, ko = r >> 6, ci = r & 63;
        wt1[j] = f2bits(W1[(ko * 64 + ci) * 9 + t]);
    } else if (i < 36864 + 18432 + 73728 + 64) {
        zb[i - 129024] = 0.0f;
    }
}

// ---- x (64,32,64,64) f32 NCHW -> xT (64,64,64,32) bf16 NHWC ---------------
__global__ void transpose_kernel(const float* __restrict__ x, u16* __restrict__ xT) {
    const int img = blockIdx.x >> 6, h = blockIdx.x & 63;
    const int gq = threadIdx.x & 3, w = threadIdx.x >> 2;
    short8 o;
#pragma unroll
    for (int k = 0; k < 8; ++k)
        o[k] = (short)f2bits(x[((size_t)img * 32 + gq * 8 + k) * 4096 + h * 64 + w]);
    ((short8*)xT)[((size_t)(img * 64 + h) * 64 + w) * 4 + gq] = o;
}

// ---- MFMA implicit-GEMM 3x3 conv, pad 1, NHWC -----------------------------
// X (64,64,64,CI) bf16 NHWC; wt [9][KO][CI] bf16; bias (KO) f32;
// Y (64,64,64,KO) bf16 NHWC. Block 256 = 4 waves; one image x 4-row strip.
// grid: 1024 1-D, XCD-chunked swizzle (T1): XCD k owns images [8k, 8k+8) so
// halo rows + the 147KB weight set stay in one XCD's (private) L2.
// Staging loads are nontemporal (evict-first) so the input stream does not
// evict the constantly re-touched weights from L2.
// Stores: nt for CI==32 kernels, plain for CI==64 (designed A/B on the
// 4.4x WRITE_SIZE amplification; both 128-ch kernels write 67MB ideal).
template<int CI, int KO>
__global__ __launch_bounds__(256, 2)
void conv3x3_mfma_kernel(const u16* __restrict__ X, const u16* __restrict__ wt,
                         const float* __restrict__ bias, u16* __restrict__ Y) {
    constexpr int CG  = CI / 8;            // 16B ci-granules per pixel
    constexpr int CGS = (CG == 4) ? 2 : 3; // log2(CG)
    constexpr int KPW = KO / 64;
    constexpr int NG  = KO / 8;            // 16B ko-granules per pixel (out)
    constexpr int PXS = NG + 1;            // padded pixel stride (granules)
    constexpr int SG  = 6 * 66 * CG;       // staging granules
    constexpr int EPG = 128 * PXS;         // epilogue granules (2 rows x 64 px)
    constexpr int LSZ = (SG > EPG) ? SG : EPG;
    constexpr bool USE_NT = (CI == 32);    // A/B: plain stores on CI=64
    __shared__ short8 lds[LSZ];

    const int l   = threadIdx.x & 63;
    const int wv  = threadIdx.x >> 6;
    const int c16 = l & 15;
    const int q16 = l >> 4;

    // XCD-chunked swizzle: dispatch d -> XCD d%8 (round-robin); give XCD k
    // the contiguous work chunk [k*128, (k+1)*128) = 8 whole images.
    const int d    = blockIdx.x;
    const int work = ((d & 7) << 7) | (d >> 3);
    const int h0   = (work & 15) * 4;
    const int n    = work >> 4;

    // zero staging LDS (borders + out-of-range rows stay zero)
    {
        const short8 z = {0, 0, 0, 0, 0, 0, 0, 0};
        for (int i = threadIdx.x; i < SG; i += 256) lds[i] = z;
    }
    __syncthreads();

    // stage rows h0-1..h0+4: contiguous 16B granule loads + swizzled ds_write
    const short8* Xg = (const short8*)X;
    for (int task = wv; task < 6 * CG; task += 4) {
        const int r     = task >> CGS;
        const int chunk = task & (CG - 1);
        const int h     = h0 + r - 1;
        if (h >= 0 && h < 64) {
            const int colrel = chunk * (64 / CG) + (l >> CGS);
            const int q      = l & (CG - 1);
            const int col    = 1 + colrel;
            const short8 v = __builtin_nontemporal_load(
                Xg + ((size_t)(n * 64 + h) * 64 + colrel) * CG + q);
            lds[(r * 66 + col) * CG + ((q + col) & (CG - 1))] = v;
        }
    }
    __syncthreads();

    const int kogb = wv * KPW;
    floatx4 acc[KPW][16];
#pragma unroll
    for (int kpw = 0; kpw < KPW; ++kpw) {
        const floatx4 init = *(const floatx4*)(bias + (kogb + kpw) * 16 + q16 * 4);
#pragma unroll
        for (int p = 0; p < 16; ++p) acc[kpw][p] = init;
    }

    const short8* wtv = (const short8*)wt;
#pragma unroll
    for (int ch = 0; ch < CI / 32; ++ch) {
        short8 af[KPW][9];
#pragma unroll
        for (int t = 0; t < 9; ++t)
#pragma unroll
            for (int kpw = 0; kpw < KPW; ++kpw)
                af[kpw][t] = wtv[(size_t)(t * KO + (kogb + kpw) * 16 + c16) * CG
                                 + ch * 4 + q16];
#pragma unroll
        for (int t = 0; t < 9; ++t) {
            const int dy = t / 3, dx = t - dy * 3;
#pragma unroll
            for (int p = 0; p < 16; ++p) {
                const int row = (p >> 2) + dy;
                const int col = (p & 3) * 16 + dx + c16;
                const int q   = ch * 4 + q16;
                const short8 bf = lds[(row * 66 + col) * CG + ((q + col) & (CG - 1))];
#pragma unroll
                for (int kpw = 0; kpw < KPW; ++kpw)
                    acc[kpw][p] = __builtin_amdgcn_mfma_f32_16x16x32_bf16(
                        af[kpw][t], bf, acc[kpw][p], 0, 0, 0);
            }
        }
    }

    // epilogue: 2 rows at a time through LDS, then fully-coalesced stores
    shortx4* lq = (shortx4*)lds;
#pragma unroll
    for (int rp = 0; rp < 2; ++rp) {
        __syncthreads();   // staging (rp=0) / previous readback (rp=1) done
#pragma unroll
        for (int kpw = 0; kpw < KPW; ++kpw) {
            const int qoff = (kogb + kpw) * 4 + q16;
#pragma unroll
            for (int pp = 0; pp < 8; ++pp) {
                const int p   = rp * 8 + pp;
                const int pxl = ((p >> 2) & 1) * 64 + (p & 3) * 16 + c16;
                shortx4 ov;
#pragma unroll
                for (int r = 0; r < 4; ++r) ov[r] = (short)f2bits(acc[kpw][p][r]);
                lq[pxl * (2 * PXS) + qoff] = ov;
            }
        }
        __syncthreads();
#pragma unroll
        for (int i = 0; i < NG / 2; ++i) {
            const int L  = i * 256 + (int)threadIdx.x;
            const int px = L / NG, g = L % NG;
            const int h  = h0 + 2 * rp + (px >> 6);
            const int w  = px & 63;
            const short8 v = lds[px * PXS + g];
            short8* dst = (short8*)Y + ((size_t)(n * 64 + h) * 64 + w) * NG + g;
            if (USE_NT) __builtin_nontemporal_store(v, dst);
            else        *dst = v;
        }
    }
}

// ---- minGRU scan + residual, full batch, NHWC -----------------------------
// Yg (64,4096,128) bf16 NHWC: gate ch [0,64), hidden [64,128). R (64,4096,64).
// FINAL=0: out = x1 bf16 NHWC. FINAL=1: out = f32 NCHW via LDS transpose.
// hlast (B,64,HW) f32 via LDS transpose. Block: 16 hw x 16 cg.
template<bool FINAL>
__global__ void gru_kernel(const u16* __restrict__ Yg, const u16* __restrict__ R,
                           void* __restrict__ outp, float* __restrict__ hlast) {
    __shared__ float lds_t[16 * 68];
    const int cg  = threadIdx.x & 15;
    const int hwl = threadIdx.x >> 4;
    const int b   = blockIdx.x >> 8;
    const int hwh = blockIdx.x & 255;
    const int hw  = hwh * 16 + hwl;
    const shortx4* Yv = (const shortx4*)Yg;
    const shortx4* Rv = (const shortx4*)R;
    float h[4] = {0.5f, 0.5f, 0.5f, 0.5f};
#pragma unroll
    for (int s = 0; s < SS; ++s) {
        const size_t px = (size_t)(b * 16 + s) * 4096 + hw;
        const shortx4 g4 = Yv[px * 32 + cg];
        const shortx4 d4 = Yv[px * 32 + 16 + cg];
        const shortx4 r4 = Rv[px * 16 + cg];
        float o[4];
#pragma unroll
        for (int j = 0; j < 4; ++j) {
            const float g   = bits2f((u16)g4[j]);
            const float hid = bits2f((u16)d4[j]);
            const float z   = 1.0f / (1.0f + __expf(-g));
            const float gg  = (hid >= 0.0f) ? (hid + 0.5f) : (1.0f / (1.0f + __expf(-hid)));
            h[j] = h[j] + z * (gg - h[j]);             // (1-z)*h + z*gg
            o[j] = h[j] + bits2f((u16)r4[j]);
        }
        if (!FINAL) {
            shortx4 ov;
#pragma unroll
            for (int j = 0; j < 4; ++j) ov[j] = (short)f2bits(o[j]);
            ((shortx4*)outp)[px * 16 + cg] = ov;
        } else {
            floatx4 o4;
#pragma unroll
            for (int j = 0; j < 4; ++j) o4[j] = o[j];
            *(floatx4*)(&lds_t[hwl * 68 + cg * 4]) = o4;
            __syncthreads();
            const int c2 = threadIdx.x >> 2, h4 = threadIdx.x & 3;
            floatx4 v;
#pragma unroll
            for (int k = 0; k < 4; ++k) v[k] = lds_t[(h4 * 4 + k) * 68 + c2];
            *(floatx4*)((float*)outp +
                        ((size_t)(b * 16 + s) * 64 + c2) * 4096 + hwh * 16 + h4 * 4) = v;
            __syncthreads();
        }
    }
    // hlast: per-thread NHWC regs -> NCHW f32 via LDS transpose (64B segments)
    {
        floatx4 h4v;
#pragma unroll
        for (int j = 0; j < 4; ++j) h4v[j] = h[j];
        if (!FINAL) __syncthreads();   // FINAL path already synced at loop end
        *(floatx4*)(&lds_t[hwl * 68 + cg * 4]) = h4v;
        __syncthreads();
        const int c2 = threadIdx.x >> 2, h4 = threadIdx.x & 3;
        floatx4 v;
#pragma unroll
        for (int k = 0; k < 4; ++k) v[k] = lds_t[(h4 * 4 + k) * 68 + c2];
        *(floatx4*)(hlast + ((size_t)b * 64 + c2) * 4096 + hwh * 16 + h4 * 4) = v;
    }
}

extern "C" void kernel_launch(void* const* d_in, const int* in_sizes, int n_in,
                              void* d_out, int out_size, void* d_ws, size_t ws_size,
                              hipStream_t stream) {
    const float* x  = (const float*)d_in[0];   // (4,16,32,64,64)
    const float* W0 = (const float*)d_in[1];   // (128,32,3,3)
    const float* b0 = (const float*)d_in[2];   // (128,)
    const float* R0 = (const float*)d_in[3];   // (64,32,3,3)
    const float* W1 = (const float*)d_in[4];   // (128,64,3,3)
    const float* b1 = (const float*)d_in[5];   // (128,)

    float* out = (float*)d_out;                 // (4,16,64,64,64) NCHW f32
    float* h0o = out + (size_t)16777216;
    float* h1o = h0o + (size_t)1048576;

    char* ws = (char*)d_ws;
    u16*   wt0 = (u16*)ws;                              // 73,728 B
    u16*   wtR = (u16*)(ws + 73728);                    // 36,864 B
    u16*   wt1 = (u16*)(ws + 110592);                   // 147,456 B
    float* zb  = (float*)(ws + 258048);                 // 256 B
    u16*   xT  = (u16*)(ws + (size_t)(1  << 20));       // 16 MiB (NHWC bf16 input)
    u16*   x1  = xT;                                    // 32 MiB; overwrites xT after convs
    u16*   y0  = (u16*)(ws + (size_t)(33 << 20));       // 64 MiB (NHWC 128ch)
    u16*   r0  = (u16*)(ws + (size_t)(97 << 20));       // 32 MiB (NHWC 64ch) -> ends 129 MiB

    prep_kernel<<<505, 256, 0, stream>>>(W0, R0, W1, wt0, wtR, wt1, zb);
    transpose_kernel<<<4096, 256, 0, stream>>>(x, xT);

    // Layer 0 (full batch): gate/hidden conv + residual conv + scan -> x1
    conv3x3_mfma_kernel<32, 128><<<1024, 256, 0, stream>>>(xT, wt0, b0, y0);
    conv3x3_mfma_kernel<32, 64 ><<<1024, 256, 0, stream>>>(xT, wtR, zb, r0);
    gru_kernel<false><<<1024, 256, 0, stream>>>(y0, r0, x1, h0o);

    // Layer 1: conv from x1 -> y0 (reuse), scan with identity residual -> out
    conv3x3_mfma_kernel<64, 128><<<1024, 256, 0, stream>>>(x1, wt1, b1, y0);
    gru_kernel<true ><<<1024, 256, 0, stream>>>(y0, x1, out, h1o);
}